// Round 13
// baseline (193.203 us; speedup 1.0000x reference)
//
#include <hip/hip_runtime.h>
#include <math.h>

#define NATOMS 1536
#define NSPEC 8
#define HID 64
#define NCEN 32
#define CUTOFF_R 5.0f
#define PI_F 3.14159265358979323846f
#define NBR_CAP 1024   // max in-cutoff neighbors per atom (~560 worst case here)
#define PREP_BLOCKS 65
#define TAIL_GRID 1024

typedef __attribute__((ext_vector_type(8))) short short8;   // 8 bf16
typedef __attribute__((ext_vector_type(4))) float float4v;  // MFMA C/D

__device__ __forceinline__ float silu_f(float x) {
    return x / (1.f + __expf(-x));
}
__device__ __forceinline__ short f2bf(float x) {   // RNE f32->bf16
    unsigned u = __float_as_uint(x);
    u += 0x7fffu + ((u >> 16) & 1u);
    return (short)(u >> 16);
}
__device__ __forceinline__ float cut_f(float d) {
    return 0.5f * (__cosf((PI_F / CUTOFF_R) * d) + 1.f);
}

// ---------------------------------------------------------------------------
// K1: blocks 0..1535: per-atom work. Blocks 1536..1600: prep (ctab, bw1, bw2).
// Counting sort groups neighbors by species so phase 2 has no cndmask selects.
// ---------------------------------------------------------------------------
__global__ __launch_bounds__(256) void k_local(
    const int* __restrict__ species, const float* __restrict__ pos,
    const float* __restrict__ tq, const float* __restrict__ embed,
    const float* __restrict__ cW1, const float* __restrict__ cb1,
    const float* __restrict__ cW2, const float* __restrict__ cb2,
    const float* __restrict__ cW3, const float* __restrict__ cb3,
    const float* __restrict__ charge_scale,
    const float* __restrict__ W1, const float* __restrict__ b1,
    const float* __restrict__ W2,
    float* __restrict__ ctab, short* __restrict__ bw1, short* __restrict__ bw2,
    float* __restrict__ raw, double* __restrict__ rsum,
    unsigned int* __restrict__ pcount, uint2* __restrict__ pdlist)
{
    __shared__ float2 dc_l[NBR_CAP];            // 8 KB  (d, cut) unsorted
    __shared__ float2 dc2[NBR_CAP];             // 8 KB  (d, cut) species-sorted
    __shared__ unsigned short spj_l[NBR_CAP];   // 2 KB  (species<<11 | j)
    __shared__ unsigned short pj_l[NBR_CAP];    // 2 KB  (neighbor-list index)
    __shared__ float s_part[8 * 256];           // 8 KB  (buckets, then partials)
    __shared__ float s_x[292];                  // feature vector
    __shared__ float s_h[64];
    __shared__ unsigned s_cnt8[8], s_off[9], s_pos[8];
    __shared__ unsigned n_cnt, p_cnt, s_base;

    const int t = threadIdx.x;

    // ---------------- prep blocks ----------------
    if (blockIdx.x >= NATOMS) {
        const int b = blockIdx.x - NATOMS;
        if (b < 64) {
            if (t < 64) {
                const int c = b;                  // combo = si*8+sj
                const int si2 = c >> 3, sj2 = c & 7;
                const int o = t;
                float acc = b1[o];
                #pragma unroll 4
                for (int k = 0; k < 32; k++) {
                    const float a = embed[si2 * 32 + k];
                    const float bb = embed[sj2 * 32 + k];
                    acc += (a + bb) * W1[(32 + k) * HID + o];
                    acc += (a * bb) * W1[(64 + k) * HID + o];
                }
                ctab[c * HID + o] = acc;
            }
        } else {
            for (int e = t; e < 2048; e += 256) {
                const int tile = e >> 9, L = (e >> 3) & 63, j = e & 7;
                const int k = (L >> 4) * 8 + j;
                const int n = tile * 16 + (L & 15);
                bw1[e] = f2bf(W1[k * HID + n]);
            }
            for (int e = t; e < 4096; e += 256) {
                const int ct = e >> 9, L = (e >> 3) & 63, j = e & 7;
                const int c = ct >> 2, tile = ct & 3;
                const int k = c * 32 + (L >> 4) * 8 + j;
                const int n = tile * 16 + (L & 15);
                bw2[e] = f2bf(W2[k * HID + n]);
            }
        }
        return;
    }

    const int i = blockIdx.x;
    const int lane = t & 63;
    if (t == 0) { n_cnt = 0u; p_cnt = 0u; }
    if (t < 8) s_cnt8[t] = 0u;
    __syncthreads();

    const float xi = pos[3*i+0], yi = pos[3*i+1], zi = pos[3*i+2];
    const int si = species[i];

    // ---- phase 1: neighbor compaction ----
    #pragma unroll
    for (int j0 = 0; j0 < NATOMS; j0 += 256) {
        const int j = j0 + t;
        const float dx = xi - pos[3*j+0];
        const float dy = yi - pos[3*j+1];
        const float dz = zi - pos[3*j+2];
        const float d = sqrtf(dx*dx + dy*dy + dz*dz + 1e-12f);
        const bool within = (d < CUTOFF_R) && (j != i);
        const unsigned long long m = __ballot((int)within);
        if (within) {
            const unsigned prefix = (unsigned)__popcll(m & ((1ull << lane) - 1ull));
            unsigned base = 0;
            if (prefix == 0) base = atomicAdd(&n_cnt, (unsigned)__popcll(m));
            base = (unsigned)__builtin_amdgcn_readfirstlane((int)base);
            const unsigned ofs = base + prefix;
            if (ofs < NBR_CAP) {
                dc_l[ofs] = make_float2(d, cut_f(d));
                spj_l[ofs] = (unsigned short)((species[j] << 11) | j);
            }
        }
    }
    __syncthreads();
    const unsigned cnt = (n_cnt < NBR_CAP) ? n_cnt : NBR_CAP;

    // ---- phase 1b: pair list (j > i), store neighbor-list index ----
    for (unsigned n0 = 0; n0 < cnt; n0 += 256) {
        const unsigned n = n0 + (unsigned)t;
        bool app = false;
        if (n < cnt) app = ((int)(spj_l[n] & 2047u) > i);
        const unsigned long long m = __ballot((int)app);
        if (app) {
            const unsigned prefix = (unsigned)__popcll(m & ((1ull << lane) - 1ull));
            unsigned base = 0;
            if (prefix == 0) base = atomicAdd(&p_cnt, (unsigned)__popcll(m));
            base = (unsigned)__builtin_amdgcn_readfirstlane((int)base);
            pj_l[base + prefix] = (unsigned short)n;
        }
    }
    __syncthreads();
    if (t == 0) s_base = atomicAdd(pcount, p_cnt);
    __syncthreads();
    {
        const unsigned pc = p_cnt, base = s_base;
        for (unsigned idx = (unsigned)t; idx < pc; idx += 256) {
            const unsigned n = pj_l[idx];
            const unsigned w = spj_l[n];
            const unsigned jj = w & 2047u, spj = w >> 11;
            uint2 pd;
            pd.x = (((unsigned)si * 8u + spj) << 22) | ((unsigned)i << 11) | jj;
            pd.y = __float_as_uint(dc_l[n].x);
            pdlist[base + idx] = pd;
        }
    }

    // ---- phase 1.5: counting sort by species ----
    for (unsigned n = (unsigned)t; n < cnt; n += 256)
        atomicAdd(&s_cnt8[spj_l[n] >> 11], 1u);
    __syncthreads();
    if (t == 0) {
        unsigned run = 0;
        #pragma unroll
        for (int s = 0; s < 8; s++) { s_off[s] = run; s_pos[s] = run; run += s_cnt8[s]; }
        s_off[8] = run;
    }
    __syncthreads();
    for (unsigned n = (unsigned)t; n < cnt; n += 256) {
        const unsigned sp = spj_l[n] >> 11;
        const unsigned dst = atomicAdd(&s_pos[sp], 1u);
        dc2[dst] = dc_l[n];
    }
    __syncthreads();

    // ---- phase 2: segment-walk basis accumulation (no species selects) ----
    {
        const int k = t & 31, gg = t >> 5;
        const float ck = (float)k * (CUTOFF_R / 31.f);
        #pragma unroll
        for (int s = 0; s < 8; s++) {
            const unsigned e0 = s_off[s], e1 = s_off[s + 1];
            float a = 0.f;
            #pragma unroll 2
            for (unsigned n = e0 + (unsigned)gg; n < e1; n += 8) {
                const float2 dc = dc2[n];
                const float diff = dc.x - ck;
                a += __expf(-4.f * diff * diff) * dc.y;
            }
            s_part[gg * 256 + s * 32 + k] = a;
        }
    }
    __syncthreads();
    {
        float acc = 0.f;
        #pragma unroll
        for (int g2 = 0; g2 < 8; g2++) acc += s_part[g2 * 256 + t];
        s_x[t] = acc;
        if (t < 32) s_x[256 + t] = embed[si * 32 + t];
        if (t == 0) s_x[288] = tq[0];
    }
    __syncthreads();

    // ---- phase 3: charge MLP over s_x[289] ----
    {
        const int g3 = t >> 6, o = t & 63;
        const int k0 = g3 * 72;
        const int k1 = (g3 == 3) ? 289 : (k0 + 72);
        float acc = 0.f;
        #pragma unroll 8
        for (int k = k0; k < k1; k++) acc += s_x[k] * cW1[k * 64 + o];
        s_part[g3 * 64 + o] = acc;
    }
    __syncthreads();
    if (t < 64) {
        const float a = cb1[t] + s_part[t] + s_part[64 + t]
                      + s_part[128 + t] + s_part[192 + t];
        s_h[t] = silu_f(a);
    }
    __syncthreads();
    {
        const int g3 = t >> 6, o = t & 63;
        float acc = 0.f;
        #pragma unroll
        for (int kk = 0; kk < 16; kk++) {
            const int k = g3 * 16 + kk;
            acc += s_h[k] * cW2[k * 64 + o];
        }
        s_part[g3 * 64 + o] = acc;
    }
    __syncthreads();
    if (t < 64) {
        const float a = cb2[t] + s_part[t] + s_part[64 + t]
                      + s_part[128 + t] + s_part[192 + t];
        float v = silu_f(a) * cW3[t];
        #pragma unroll
        for (int off = 32; off > 0; off >>= 1) v += __shfl_down(v, off);
        if (t == 0) {
            const float rawv = (v + cb3[0]) * charge_scale[0];
            raw[i] = rawv;
            atomicAdd(rsum, (double)rawv);
        }
    }
}

// ---------------------------------------------------------------------------
// K2 (k_tail): ALL blocks run the MFMA pair MLP (grid-stride), then all share
// LR coulomb + charges (+bias on block 0). No shfl broadcasts; ctab in LDS.
// NOTE: pair loop must stay unroll-1 — unroll 2 doubles the ~100-reg live set
// and spilled 4.2 MB/dispatch to scratch in R12 (WRITE_SIZE 70 KB -> 4.2 MB).
// ---------------------------------------------------------------------------
__global__ __launch_bounds__(256, 4) void k_tail(
    const int* __restrict__ species, const float* __restrict__ pos,
    const float* __restrict__ raw, const float* __restrict__ tq,
    const float* __restrict__ softening, const float* __restrict__ atom_bias,
    const float* __restrict__ coulomb_scale,
    const float* __restrict__ b2, const float* __restrict__ W3,
    const float* __restrict__ b3, const float* __restrict__ ctab,
    const short* __restrict__ bw1, const short* __restrict__ bw2,
    const unsigned int* __restrict__ pcount, const uint2* __restrict__ pdlist,
    const double* __restrict__ rsum,
    double* __restrict__ e_pair, double* __restrict__ e_lr,
    double* __restrict__ bias_d, unsigned int* __restrict__ done,
    float* __restrict__ out_energy, float* __restrict__ charges)
{
    __shared__ float s_ctab[64 * 65];    // 16.6 KB, stride-65 pad
    __shared__ float s_tp[4][16 * 66];   // 16.9 KB
    __shared__ float s_red[256];
    const int t = threadIdx.x;
    const int lane = t & 63;
    const int wid = t >> 6;
    const int col = lane & 15;
    const int quad = lane >> 4;

    // stage ctab into LDS
    for (int e = t; e < 4096; e += 256) {
        const int c = e >> 6, o = e & 63;
        s_ctab[c * 65 + o] = ctab[e];
    }

    // loop-invariant weight fragments
    const short8* __restrict__ bw1v = (const short8*)bw1;
    const short8* __restrict__ bw2v = (const short8*)bw2;
    short8 w1f[4], w2f[8];
    #pragma unroll
    for (int t4 = 0; t4 < 4; t4++) w1f[t4] = bw1v[t4 * 64 + lane];
    #pragma unroll
    for (int q8 = 0; q8 < 8; q8++) w2f[q8] = bw2v[q8 * 64 + lane];
    float b2l[4], w3l[4];
    #pragma unroll
    for (int t4 = 0; t4 < 4; t4++) { b2l[t4] = b2[t4*16+col]; w3l[t4] = W3[t4*16+col]; }
    const float b3v = b3[0];
    const unsigned cnt = *pcount;
    float* tb = &s_tp[wid][0];
    __syncthreads();

    // ---------------- pair MLP (all blocks) ----------------
    float esum = 0.f;
    const unsigned wstep = TAIL_GRID * 4u;
    #pragma unroll 1
    for (unsigned w = blockIdx.x * 4u + (unsigned)wid; w * 16u < cnt; w += wstep) {
        // own pair (for A fragment)
        unsigned own_idx = w * 16u + (unsigned)col;
        const bool own_ok = own_idx < cnt;
        if (!own_ok) own_idx = cnt - 1;
        const uint2 pdo = pdlist[own_idx];
        const float d_own = __uint_as_float(pdo.y);
        const float cut_own = own_ok ? cut_f(d_own) : 0.f;
        if (lane < 16) esum += b3v * cut_own;

        // row pairs (for C init / epilogue) — same 128B line, L1 broadcast
        int cmb[4]; float cutr[4];
        #pragma unroll
        for (int r = 0; r < 4; r++) {
            unsigned ridx = w * 16u + (unsigned)(quad * 4 + r);
            const bool rok = ridx < cnt;
            if (!rok) ridx = cnt - 1;
            const uint2 pdr = pdlist[ridx];
            cmb[r] = (int)(pdr.x >> 22);
            cutr[r] = rok ? cut_f(__uint_as_float(pdr.y)) : 0.f;
        }

        short8 a1f;
        #pragma unroll
        for (int jj = 0; jj < 8; jj++) {
            const float ck = (float)(quad * 8 + jj) * (CUTOFF_R / 31.f);
            const float diff = d_own - ck;
            a1f[jj] = f2bf(__expf(-4.f * diff * diff));
        }

        float4v acc[4];
        #pragma unroll
        for (int t4 = 0; t4 < 4; t4++) {
            #pragma unroll
            for (int r = 0; r < 4; r++)
                acc[t4][r] = s_ctab[cmb[r] * 65 + t4 * 16 + col];
        }
        #pragma unroll
        for (int t4 = 0; t4 < 4; t4++)
            acc[t4] = __builtin_amdgcn_mfma_f32_16x16x32_bf16(a1f, w1f[t4], acc[t4], 0, 0, 0);

        #pragma unroll
        for (int t4 = 0; t4 < 4; t4++) {
            #pragma unroll
            for (int r = 0; r < 4; r++)
                tb[(quad * 4 + r) * 66 + t4 * 16 + col] = silu_f(acc[t4][r]);
        }
        short8 a2f[2];
        #pragma unroll
        for (int c = 0; c < 2; c++) {
            #pragma unroll
            for (int jj = 0; jj < 8; jj++)
                a2f[c][jj] = f2bf(tb[col * 66 + c * 32 + quad * 8 + jj]);
        }

        float4v acc2[4];
        #pragma unroll
        for (int t4 = 0; t4 < 4; t4++) {
            acc2[t4][0] = b2l[t4]; acc2[t4][1] = b2l[t4];
            acc2[t4][2] = b2l[t4]; acc2[t4][3] = b2l[t4];
        }
        #pragma unroll
        for (int c = 0; c < 2; c++) {
            #pragma unroll
            for (int t4 = 0; t4 < 4; t4++)
                acc2[t4] = __builtin_amdgcn_mfma_f32_16x16x32_bf16(a2f[c], w2f[c*4+t4], acc2[t4], 0, 0, 0);
        }

        #pragma unroll
        for (int r = 0; r < 4; r++) {
            float part = 0.f;
            #pragma unroll
            for (int t4 = 0; t4 < 4; t4++) part += silu_f(acc2[t4][r]) * w3l[t4];
            esum += part * cutr[r];
        }
    }

    s_red[t] = esum;
    __syncthreads();
    for (int s = 128; s > 0; s >>= 1) { if (t < s) s_red[t] += s_red[t + s]; __syncthreads(); }
    if (t == 0 && s_red[0] != 0.f) atomicAdd(e_pair, (double)s_red[0]);
    __syncthreads();

    // ---------------- bias (block 0) ----------------
    if (blockIdx.x == 0) {
        float acc = 0.f;
        for (int idx = t; idx < NATOMS; idx += 256) acc += atom_bias[species[idx]];
        s_red[t] = acc;
        __syncthreads();
        for (int s = 128; s > 0; s >>= 1) { if (t < s) s_red[t] += s_red[t + s]; __syncthreads(); }
        if (t == 0) atomicAdd(bias_d, (double)s_red[0]);
        __syncthreads();
    }

    // ---------------- charges + LR (all blocks) ----------------
    const float mean = (float)(rsum[0] / (double)NATOMS);
    const float add = tq[0] / (float)NATOMS;
    {
        const int gid = blockIdx.x * 256 + t;
        if (gid < NATOMS) charges[gid] = raw[gid] - mean + add;
    }
    {
        const float sr = softening[0];
        const float sp = ((sr > 20.f) ? sr : log1pf(__expf(sr))) + 0.001f;
        const float sp2 = sp * sp;
        float acc = 0.f;
        for (int i = blockIdx.x; i < NATOMS; i += TAIL_GRID) {
            const float xi = pos[3*i+0], yi = pos[3*i+1], zi = pos[3*i+2];
            const float qi = raw[i] - mean + add;
            for (int j = i + 1 + t; j < NATOMS; j += 256) {
                const float dx = xi - pos[3*j+0];
                const float dy = yi - pos[3*j+1];
                const float dz = zi - pos[3*j+2];
                const float d2 = dx*dx + dy*dy + dz*dz + 1e-12f;
                const float qj = raw[j] - mean + add;
                acc += qi * qj * rsqrtf(d2 + sp2);
            }
        }
        s_red[t] = acc;
        __syncthreads();
        for (int s = 128; s > 0; s >>= 1) { if (t < s) s_red[t] += s_red[t + s]; __syncthreads(); }
        if (t == 0 && s_red[0] != 0.f) atomicAdd(e_lr, (double)s_red[0]);
    }

    // ---------------- ticket finale ----------------
    if (t == 0) {
        __threadfence();
        const unsigned ticket = atomicAdd(done, 1u);
        if (ticket == (unsigned)TAIL_GRID - 1u) {
            __threadfence();
            const double ep = atomicAdd(e_pair, 0.0);
            const double el = atomicAdd(e_lr, 0.0);
            const double bd = atomicAdd(bias_d, 0.0);
            out_energy[0] = (float)(ep + (double)coulomb_scale[0] * el + bd);
        }
    }
}

// ---------------------------------------------------------------------------
extern "C" void kernel_launch(void* const* d_in, const int* in_sizes, int n_in,
                              void* d_out, int out_size, void* d_ws, size_t ws_size,
                              hipStream_t stream) {
    const int*   species       = (const int*)d_in[0];
    const float* pos           = (const float*)d_in[1];
    const float* tq            = (const float*)d_in[2];
    const float* embed         = (const float*)d_in[3];
    const float* W1            = (const float*)d_in[4];
    const float* b1            = (const float*)d_in[5];
    const float* W2            = (const float*)d_in[6];
    const float* b2            = (const float*)d_in[7];
    const float* W3            = (const float*)d_in[8];
    const float* b3            = (const float*)d_in[9];
    const float* atom_bias     = (const float*)d_in[10];
    const float* cW1           = (const float*)d_in[11];
    const float* cb1           = (const float*)d_in[12];
    const float* cW2           = (const float*)d_in[13];
    const float* cb2           = (const float*)d_in[14];
    const float* cW3           = (const float*)d_in[15];
    const float* cb3           = (const float*)d_in[16];
    const float* charge_scale  = (const float*)d_in[17];
    const float* coulomb_scale = (const float*)d_in[18];
    const float* softening     = (const float*)d_in[19];

    char* ws = (char*)d_ws;
    double*   e_pair   = (double*)(ws + 0);
    double*   e_lr     = (double*)(ws + 8);
    unsigned* pcount   = (unsigned*)(ws + 16);
    unsigned* done     = (unsigned*)(ws + 20);
    double*   rsum     = (double*)(ws + 24);
    double*   bias_d   = (double*)(ws + 32);
    float*    raw      = (float*)(ws + 64);      // 6144 B
    float*    ctab     = (float*)(ws + 8192);    // 16384 B
    short*    bw1      = (short*)(ws + 24576);   // 4096 B
    short*    bw2      = (short*)(ws + 28672);   // 8192 B
    uint2*    pdlist   = (uint2*)(ws + 40960);   // ~1.4 MB

    float* out     = (float*)d_out;
    float* charges = out + 1;   // output layout: [energy, charges[1536]]

    hipMemsetAsync(d_ws, 0, 40, stream);  // e_pair, e_lr, pcount, done, rsum, bias_d

    k_local<<<NATOMS + PREP_BLOCKS, 256, 0, stream>>>(
        species, pos, tq, embed,
        cW1, cb1, cW2, cb2, cW3, cb3, charge_scale,
        W1, b1, W2, ctab, bw1, bw2,
        raw, rsum, pcount, pdlist);
    k_tail<<<TAIL_GRID, 256, 0, stream>>>(
        species, pos, raw, tq, softening, atom_bias, coulomb_scale,
        b2, W3, b3, ctab, bw1, bw2, pcount, pdlist, rsum,
        e_pair, e_lr, bias_d, done, out, charges);
}

// Round 14
// 167.071 us; speedup vs baseline: 1.1564x; 1.1564x over previous
//
#include <hip/hip_runtime.h>
#include <math.h>

#define NATOMS 1536
#define NSPEC 8
#define HID 64
#define NCEN 32
#define CUTOFF_R 5.0f
#define PI_F 3.14159265358979323846f
#define NBR_CAP 1024   // max in-cutoff neighbors per atom (~560 worst case here)
#define PREP_BLOCKS 65
#define PAIR_B 768     // k_tail: blocks 0..767 pair MLP, 768..1023 LR+charges
#define TAIL_GRID 1024

typedef __attribute__((ext_vector_type(8))) short short8;   // 8 bf16
typedef __attribute__((ext_vector_type(4))) float float4v;  // MFMA C/D

__device__ __forceinline__ float silu_f(float x) {
    return x / (1.f + __expf(-x));
}
__device__ __forceinline__ short f2bf(float x) {   // RNE f32->bf16
    unsigned u = __float_as_uint(x);
    u += 0x7fffu + ((u >> 16) & 1u);
    return (short)(u >> 16);
}
__device__ __forceinline__ float cut_f(float d) {
    return 0.5f * (__cosf((PI_F / CUTOFF_R) * d) + 1.f);
}

// ---------------------------------------------------------------------------
// K1: blocks 0..1535: per-atom work. Blocks 1536..1600: prep (ctab, bw1, bw2).
// R11-proven form: register-bucket phase 2 (LDS atomics regressed 2.5x, R10),
// uint2 pdlist carries d so k_tail needs no pos gather.
// ---------------------------------------------------------------------------
__global__ __launch_bounds__(256) void k_local(
    const int* __restrict__ species, const float* __restrict__ pos,
    const float* __restrict__ tq, const float* __restrict__ embed,
    const float* __restrict__ cW1, const float* __restrict__ cb1,
    const float* __restrict__ cW2, const float* __restrict__ cb2,
    const float* __restrict__ cW3, const float* __restrict__ cb3,
    const float* __restrict__ charge_scale,
    const float* __restrict__ W1, const float* __restrict__ b1,
    const float* __restrict__ W2,
    float* __restrict__ ctab, short* __restrict__ bw1, short* __restrict__ bw2,
    float* __restrict__ raw, double* __restrict__ rsum,
    unsigned int* __restrict__ pcount, uint2* __restrict__ pdlist)
{
    __shared__ float2 dc_l[NBR_CAP];            // 8 KB  (d, cut)
    __shared__ unsigned short spj_l[NBR_CAP];   // 2 KB  (species<<11 | j)
    __shared__ unsigned short pj_l[NBR_CAP];    // 2 KB  (neighbor-list index)
    __shared__ float s_part[8 * 256];           // 8 KB  (buckets, then partials)
    __shared__ float s_x[292];                  // feature vector
    __shared__ float s_h[64];
    __shared__ unsigned n_cnt, p_cnt, s_base;

    const int t = threadIdx.x;

    // ---------------- prep blocks ----------------
    if (blockIdx.x >= NATOMS) {
        const int b = blockIdx.x - NATOMS;
        if (b < 64) {
            if (t < 64) {
                const int c = b;                  // combo = si*8+sj
                const int si2 = c >> 3, sj2 = c & 7;
                const int o = t;
                float acc = b1[o];
                #pragma unroll 4
                for (int k = 0; k < 32; k++) {
                    const float a = embed[si2 * 32 + k];
                    const float bb = embed[sj2 * 32 + k];
                    acc += (a + bb) * W1[(32 + k) * HID + o];
                    acc += (a * bb) * W1[(64 + k) * HID + o];
                }
                ctab[c * HID + o] = acc;
            }
        } else {
            for (int e = t; e < 2048; e += 256) {
                const int tile = e >> 9, L = (e >> 3) & 63, j = e & 7;
                const int k = (L >> 4) * 8 + j;
                const int n = tile * 16 + (L & 15);
                bw1[e] = f2bf(W1[k * HID + n]);
            }
            for (int e = t; e < 4096; e += 256) {
                const int ct = e >> 9, L = (e >> 3) & 63, j = e & 7;
                const int c = ct >> 2, tile = ct & 3;
                const int k = c * 32 + (L >> 4) * 8 + j;
                const int n = tile * 16 + (L & 15);
                bw2[e] = f2bf(W2[k * HID + n]);
            }
        }
        return;
    }

    const int i = blockIdx.x;
    const int lane = t & 63;
    if (t == 0) { n_cnt = 0u; p_cnt = 0u; }
    __syncthreads();

    const float xi = pos[3*i+0], yi = pos[3*i+1], zi = pos[3*i+2];
    const int si = species[i];

    // ---- phase 1: neighbor compaction ----
    #pragma unroll
    for (int j0 = 0; j0 < NATOMS; j0 += 256) {
        const int j = j0 + t;
        const float dx = xi - pos[3*j+0];
        const float dy = yi - pos[3*j+1];
        const float dz = zi - pos[3*j+2];
        const float d = sqrtf(dx*dx + dy*dy + dz*dz + 1e-12f);
        const bool within = (d < CUTOFF_R) && (j != i);
        const unsigned long long m = __ballot((int)within);
        if (within) {
            const unsigned prefix = (unsigned)__popcll(m & ((1ull << lane) - 1ull));
            unsigned base = 0;
            if (prefix == 0) base = atomicAdd(&n_cnt, (unsigned)__popcll(m));
            base = (unsigned)__builtin_amdgcn_readfirstlane((int)base);
            const unsigned ofs = base + prefix;
            if (ofs < NBR_CAP) {
                dc_l[ofs] = make_float2(d, cut_f(d));
                spj_l[ofs] = (unsigned short)((species[j] << 11) | j);
            }
        }
    }
    __syncthreads();
    const unsigned cnt = (n_cnt < NBR_CAP) ? n_cnt : NBR_CAP;

    // ---- phase 1b: pair list (j > i), store neighbor-list index ----
    for (unsigned n0 = 0; n0 < cnt; n0 += 256) {
        const unsigned n = n0 + (unsigned)t;
        bool app = false;
        if (n < cnt) app = ((int)(spj_l[n] & 2047u) > i);
        const unsigned long long m = __ballot((int)app);
        if (app) {
            const unsigned prefix = (unsigned)__popcll(m & ((1ull << lane) - 1ull));
            unsigned base = 0;
            if (prefix == 0) base = atomicAdd(&p_cnt, (unsigned)__popcll(m));
            base = (unsigned)__builtin_amdgcn_readfirstlane((int)base);
            pj_l[base + prefix] = (unsigned short)n;
        }
    }
    __syncthreads();
    if (t == 0) s_base = atomicAdd(pcount, p_cnt);
    __syncthreads();
    {
        const unsigned pc = p_cnt, base = s_base;
        for (unsigned idx = (unsigned)t; idx < pc; idx += 256) {
            const unsigned n = pj_l[idx];
            const unsigned w = spj_l[n];
            const unsigned jj = w & 2047u, spj = w >> 11;
            uint2 pd;
            pd.x = (((unsigned)si * 8u + spj) << 22) | ((unsigned)i << 11) | jj;
            pd.y = __float_as_uint(dc_l[n].x);
            pdlist[base + idx] = pd;
        }
    }

    // ---- phase 2: register-bucket basis accumulation (R8/R11-proven) ----
    {
        const int k = t & 31, gg = t >> 5;
        const float ck = (float)k * (CUTOFF_R / 31.f);
        float f0=0.f,f1=0.f,f2=0.f,f3=0.f,f4=0.f,f5=0.f,f6=0.f,f7=0.f;
        #pragma unroll 2
        for (unsigned n = (unsigned)gg; n < cnt; n += 8) {
            const float2 dc = dc_l[n];
            const float diff = dc.x - ck;
            const float v = __expf(-4.f * diff * diff) * dc.y;
            const int sp = (int)(spj_l[n] >> 11);
            f0 += (sp == 0) ? v : 0.f;
            f1 += (sp == 1) ? v : 0.f;
            f2 += (sp == 2) ? v : 0.f;
            f3 += (sp == 3) ? v : 0.f;
            f4 += (sp == 4) ? v : 0.f;
            f5 += (sp == 5) ? v : 0.f;
            f6 += (sp == 6) ? v : 0.f;
            f7 += (sp == 7) ? v : 0.f;
        }
        float* sp_g = &s_part[gg * 256 + k];
        sp_g[0*32] = f0; sp_g[1*32] = f1; sp_g[2*32] = f2; sp_g[3*32] = f3;
        sp_g[4*32] = f4; sp_g[5*32] = f5; sp_g[6*32] = f6; sp_g[7*32] = f7;
    }
    __syncthreads();
    {
        float acc = 0.f;
        #pragma unroll
        for (int g2 = 0; g2 < 8; g2++) acc += s_part[g2 * 256 + t];
        s_x[t] = acc;
        if (t < 32) s_x[256 + t] = embed[si * 32 + t];
        if (t == 0) s_x[288] = tq[0];
    }
    __syncthreads();

    // ---- phase 3: charge MLP over s_x[289] ----
    {
        const int g3 = t >> 6, o = t & 63;
        const int k0 = g3 * 72;
        const int k1 = (g3 == 3) ? 289 : (k0 + 72);
        float acc = 0.f;
        #pragma unroll 8
        for (int k = k0; k < k1; k++) acc += s_x[k] * cW1[k * 64 + o];
        s_part[g3 * 64 + o] = acc;
    }
    __syncthreads();
    if (t < 64) {
        const float a = cb1[t] + s_part[t] + s_part[64 + t]
                      + s_part[128 + t] + s_part[192 + t];
        s_h[t] = silu_f(a);
    }
    __syncthreads();
    {
        const int g3 = t >> 6, o = t & 63;
        float acc = 0.f;
        #pragma unroll
        for (int kk = 0; kk < 16; kk++) {
            const int k = g3 * 16 + kk;
            acc += s_h[k] * cW2[k * 64 + o];
        }
        s_part[g3 * 64 + o] = acc;
    }
    __syncthreads();
    if (t < 64) {
        const float a = cb2[t] + s_part[t] + s_part[64 + t]
                      + s_part[128 + t] + s_part[192 + t];
        float v = silu_f(a) * cW3[t];
        #pragma unroll
        for (int off = 32; off > 0; off >>= 1) v += __shfl_down(v, off);
        if (t == 0) {
            const float rawv = (v + cb3[0]) * charge_scale[0];
            raw[i] = rawv;
            atomicAdd(rsum, (double)rawv);
        }
    }
}

// ---------------------------------------------------------------------------
// K2 (k_tail): R11-proven pair MLP (shfl broadcast, ctab from global — the
// R12/R13 no-shfl + ctab-LDS variant tipped the exactly-full 128-reg budget
// into true scratch: WRITE_SIZE 70KB->4.2MB). Finale de-contended: per-block
// partial slots (atomicExch, distinct addresses) + block-wide summation by
// the ticket-winner (atomic reads = coherent across XCDs).
// ---------------------------------------------------------------------------
__global__ __launch_bounds__(256, 4) void k_tail(
    const int* __restrict__ species, const float* __restrict__ pos,
    const float* __restrict__ raw, const float* __restrict__ tq,
    const float* __restrict__ softening, const float* __restrict__ atom_bias,
    const float* __restrict__ coulomb_scale,
    const float* __restrict__ b2, const float* __restrict__ W3,
    const float* __restrict__ b3, const float* __restrict__ ctab,
    const short* __restrict__ bw1, const short* __restrict__ bw2,
    const unsigned int* __restrict__ pcount, const uint2* __restrict__ pdlist,
    const double* __restrict__ rsum,
    double* __restrict__ epp, double* __restrict__ elp,
    double* __restrict__ bias_part, unsigned int* __restrict__ done,
    float* __restrict__ out_energy, float* __restrict__ charges)
{
    __shared__ float s_tp[4][16 * 66];
    __shared__ float s_red[256];
    __shared__ double s_redd[256];
    __shared__ unsigned s_ticket;
    const int t = threadIdx.x;
    const int lane = t & 63;

    if (blockIdx.x < PAIR_B) {
        // ---------------- pair MLP on the matrix pipe ----------------
        const int wid = t >> 6;
        const int col = lane & 15;
        const int quad = lane >> 4;
        const short8* __restrict__ bw1v = (const short8*)bw1;
        const short8* __restrict__ bw2v = (const short8*)bw2;
        short8 w1f[4], w2f[8];
        #pragma unroll
        for (int t4 = 0; t4 < 4; t4++) w1f[t4] = bw1v[t4 * 64 + lane];
        #pragma unroll
        for (int q8 = 0; q8 < 8; q8++) w2f[q8] = bw2v[q8 * 64 + lane];
        float b2l[4], w3l[4];
        #pragma unroll
        for (int t4 = 0; t4 < 4; t4++) { b2l[t4] = b2[t4*16+col]; w3l[t4] = W3[t4*16+col]; }
        const float b3v = b3[0];
        const unsigned cnt = *pcount;
        float* tb = &s_tp[wid][0];

        float esum = 0.f;
        const unsigned wstep = PAIR_B * 4u;
        for (unsigned w = blockIdx.x * 4u + (unsigned)wid; w * 16u < cnt; w += wstep) {
            unsigned p_idx = w * 16u + (unsigned)col;
            const bool valid = p_idx < cnt;
            if (!valid) p_idx = cnt - 1;
            const uint2 pd = pdlist[p_idx];
            const int combo = (int)(pd.x >> 22);
            const float d = __uint_as_float(pd.y);
            const float cut = valid ? cut_f(d) : 0.f;
            if (lane < 16) esum += b3v * cut;

            short8 a1f;
            #pragma unroll
            for (int jj = 0; jj < 8; jj++) {
                const float ck = (float)(quad * 8 + jj) * (CUTOFF_R / 31.f);
                const float diff = d - ck;
                a1f[jj] = f2bf(__expf(-4.f * diff * diff));
            }

            int cmb[4]; float cutr[4];
            #pragma unroll
            for (int r = 0; r < 4; r++) {
                const int p = quad * 4 + r;
                cmb[r]  = __shfl(combo, p);
                cutr[r] = __shfl(cut, p);
            }

            float4v acc[4];
            #pragma unroll
            for (int t4 = 0; t4 < 4; t4++) {
                #pragma unroll
                for (int r = 0; r < 4; r++)
                    acc[t4][r] = ctab[cmb[r] * HID + t4 * 16 + col];
            }
            #pragma unroll
            for (int t4 = 0; t4 < 4; t4++)
                acc[t4] = __builtin_amdgcn_mfma_f32_16x16x32_bf16(a1f, w1f[t4], acc[t4], 0, 0, 0);

            #pragma unroll
            for (int t4 = 0; t4 < 4; t4++) {
                #pragma unroll
                for (int r = 0; r < 4; r++)
                    tb[(quad * 4 + r) * 66 + t4 * 16 + col] = silu_f(acc[t4][r]);
            }
            short8 a2f[2];
            #pragma unroll
            for (int c = 0; c < 2; c++) {
                #pragma unroll
                for (int jj = 0; jj < 8; jj++)
                    a2f[c][jj] = f2bf(tb[col * 66 + c * 32 + quad * 8 + jj]);
            }

            float4v acc2[4];
            #pragma unroll
            for (int t4 = 0; t4 < 4; t4++) {
                acc2[t4][0] = b2l[t4]; acc2[t4][1] = b2l[t4];
                acc2[t4][2] = b2l[t4]; acc2[t4][3] = b2l[t4];
            }
            #pragma unroll
            for (int c = 0; c < 2; c++) {
                #pragma unroll
                for (int t4 = 0; t4 < 4; t4++)
                    acc2[t4] = __builtin_amdgcn_mfma_f32_16x16x32_bf16(a2f[c], w2f[c*4+t4], acc2[t4], 0, 0, 0);
            }

            #pragma unroll
            for (int r = 0; r < 4; r++) {
                float part = 0.f;
                #pragma unroll
                for (int t4 = 0; t4 < 4; t4++) part += silu_f(acc2[t4][r]) * w3l[t4];
                esum += part * cutr[r];
            }
        }

        s_red[t] = esum;
        __syncthreads();
        for (int s = 128; s > 0; s >>= 1) { if (t < s) s_red[t] += s_red[t + s]; __syncthreads(); }
        if (t == 0)   // uncontended coherent store (slot is poisoned -> must write)
            atomicExch((unsigned long long*)&epp[blockIdx.x],
                       (unsigned long long)__double_as_longlong((double)s_red[0]));
    } else {
        // ---------------- LR coulomb + charges (+bias on first) -------
        const int b = blockIdx.x - PAIR_B;      // 0..255
        const float mean = (float)(rsum[0] / (double)NATOMS);
        const float add = tq[0] / (float)NATOMS;

        if (b == 0) {
            float acc = 0.f;
            for (int idx = t; idx < NATOMS; idx += 256) acc += atom_bias[species[idx]];
            s_red[t] = acc;
            __syncthreads();
            for (int s = 128; s > 0; s >>= 1) { if (t < s) s_red[t] += s_red[t + s]; __syncthreads(); }
            if (t == 0)
                atomicExch((unsigned long long*)bias_part,
                           (unsigned long long)__double_as_longlong((double)s_red[0]));
            __syncthreads();
        }

        const int gid = b * 256 + t;
        if (gid < NATOMS) charges[gid] = raw[gid] - mean + add;

        const float sr = softening[0];
        const float sp = ((sr > 20.f) ? sr : log1pf(__expf(sr))) + 0.001f;
        const float sp2 = sp * sp;
        float acc = 0.f;
        for (int i = b; i < NATOMS; i += 256) {
            const float xi = pos[3*i+0], yi = pos[3*i+1], zi = pos[3*i+2];
            const float qi = raw[i] - mean + add;
            for (int j = i + 1 + t; j < NATOMS; j += 256) {
                const float dx = xi - pos[3*j+0];
                const float dy = yi - pos[3*j+1];
                const float dz = zi - pos[3*j+2];
                const float d2 = dx*dx + dy*dy + dz*dz + 1e-12f;
                const float qj = raw[j] - mean + add;
                acc += qi * qj * rsqrtf(d2 + sp2);
            }
        }
        s_red[t] = acc;
        __syncthreads();
        for (int s = 128; s > 0; s >>= 1) { if (t < s) s_red[t] += s_red[t + s]; __syncthreads(); }
        if (t == 0)
            atomicExch((unsigned long long*)&elp[b],
                       (unsigned long long)__double_as_longlong((double)s_red[0]));
    }

    // ---------------- ticket finale (winner block sums partials) -----
    if (t == 0) {
        __threadfence();
        s_ticket = atomicAdd(done, 1u);
    }
    __syncthreads();
    if (s_ticket == (unsigned)TAIL_GRID - 1u) {
        __threadfence();
        const double cs = (double)coulomb_scale[0];
        double acc = 0.0;
        for (int idx = t; idx < PAIR_B; idx += 256)
            acc += __longlong_as_double(
                (long long)atomicAdd((unsigned long long*)&epp[idx], 0ull));
        if (t < 256) {   // one elp slot per thread (256 slots)
            acc += cs * __longlong_as_double(
                (long long)atomicAdd((unsigned long long*)&elp[t], 0ull));
        }
        s_redd[t] = acc;
        __syncthreads();
        for (int s = 128; s > 0; s >>= 1) { if (t < s) s_redd[t] += s_redd[t + s]; __syncthreads(); }
        if (t == 0) {
            const double bd = __longlong_as_double(
                (long long)atomicAdd((unsigned long long*)bias_part, 0ull));
            out_energy[0] = (float)(s_redd[0] + bd);
        }
    }
}

// ---------------------------------------------------------------------------
extern "C" void kernel_launch(void* const* d_in, const int* in_sizes, int n_in,
                              void* d_out, int out_size, void* d_ws, size_t ws_size,
                              hipStream_t stream) {
    const int*   species       = (const int*)d_in[0];
    const float* pos           = (const float*)d_in[1];
    const float* tq            = (const float*)d_in[2];
    const float* embed         = (const float*)d_in[3];
    const float* W1            = (const float*)d_in[4];
    const float* b1            = (const float*)d_in[5];
    const float* W2            = (const float*)d_in[6];
    const float* b2            = (const float*)d_in[7];
    const float* W3            = (const float*)d_in[8];
    const float* b3            = (const float*)d_in[9];
    const float* atom_bias     = (const float*)d_in[10];
    const float* cW1           = (const float*)d_in[11];
    const float* cb1           = (const float*)d_in[12];
    const float* cW2           = (const float*)d_in[13];
    const float* cb2           = (const float*)d_in[14];
    const float* cW3           = (const float*)d_in[15];
    const float* cb3           = (const float*)d_in[16];
    const float* charge_scale  = (const float*)d_in[17];
    const float* coulomb_scale = (const float*)d_in[18];
    const float* softening     = (const float*)d_in[19];

    char* ws = (char*)d_ws;
    double*   rsum      = (double*)(ws + 0);
    double*   bias_part = (double*)(ws + 8);
    unsigned* pcount    = (unsigned*)(ws + 16);
    unsigned* done      = (unsigned*)(ws + 20);
    float*    raw       = (float*)(ws + 64);      // 6144 B
    float*    ctab      = (float*)(ws + 8192);    // 16384 B
    short*    bw1       = (short*)(ws + 24576);   // 4096 B
    short*    bw2       = (short*)(ws + 28672);   // 8192 B
    double*   epp       = (double*)(ws + 36864);  // 768 * 8 = 6144 B
    double*   elp       = (double*)(ws + 43008);  // 256 * 8 = 2048 B
    uint2*    pdlist    = (uint2*)(ws + 49152);   // ~1.4 MB

    float* out     = (float*)d_out;
    float* charges = out + 1;   // output layout: [energy, charges[1536]]

    hipMemsetAsync(d_ws, 0, 24, stream);  // rsum, bias_part, pcount, done

    k_local<<<NATOMS + PREP_BLOCKS, 256, 0, stream>>>(
        species, pos, tq, embed,
        cW1, cb1, cW2, cb2, cW3, cb3, charge_scale,
        W1, b1, W2, ctab, bw1, bw2,
        raw, rsum, pcount, pdlist);
    k_tail<<<TAIL_GRID, 256, 0, stream>>>(
        species, pos, raw, tq, softening, atom_bias, coulomb_scale,
        b2, W3, b3, ctab, bw1, bw2, pcount, pdlist, rsum,
        epp, elp, bias_part, done, out, charges);
}